// Round 10
// baseline (1939.905 us; speedup 1.0000x reference)
//
#include <hip/hip_runtime.h>
#include <math.h>

typedef unsigned short u16;
typedef unsigned int   u32;

#define LVLS 24
#define CAPN (1 << 18)
#define STR  84            // act row stride in u32: 336B = 21*16 -> 16B-aligned rows
#define NWAVES 16          // waves per block (1024 threads)
#define NPAIRS 8           // wave PAIRS; each pair owns one 16-point tile
#define TPW  16            // points per pair tile
#define ACTSZ (TPW * STR + 16)   // 1360 u32 per pair act slice

// ---- LDS layout (u32 offsets) ----
#define WB1   0
#define WB2   4096
#define WB3   8192
#define WB4   12288        /* W4 cols 1..64 */
#define WBR1  16384        /* NKT=3 */
#define WBR2  22528        /* blob end 26624 */
#define SWOFF 26624        /* 24 x {scale, window} floats  -> 48 u32 */
#define W4C   26672        /* W4 column 0 (64 floats) */
#define R3C   26736        /* R3 64x3 floats (192) */
#define SHF   26928        /* shifts 24x3 ints (72) */
#define ACT0  27008        /* 8 pair act slices of ACTSZ */
#define LDS_U32 (ACT0 + NPAIRS * ACTSZ)   /* 37888 u32 = 151552 B <= 160 KiB */

typedef float    f32x4 __attribute__((ext_vector_type(4)));
typedef _Float16 f16x8 __attribute__((ext_vector_type(8)));
typedef u32      u32x4 __attribute__((ext_vector_type(4)));

#if __has_builtin(__builtin_amdgcn_rcpf)
#define RCPF(x) __builtin_amdgcn_rcpf(x)
#else
#define RCPF(x) (1.0f / (x))
#endif
#if __has_builtin(__builtin_amdgcn_exp2f)
#define EXP2F(x) __builtin_amdgcn_exp2f(x)
#else
#define EXP2F(x) exp2f(x)
#endif

// ---- global scaling scheme (fp16-denormal avoidance; verified abs=3.9e-3) ----
// B side stored as 256*x in fp16 hi/lo; A side (weights) 256*w hi/lo blob in
// LDS; epilogue descales by 2^-16. SELF-CONTAINED: d_in -> d_out only.
//
// r10: wave-PAIR split. r9 post-mortem: TPW=8 doubled per-point VALU work
// (dup B-cols -> 2x MFMA; 8x redundant hash prelude) -> VALU 76%, SLOWER.
// Constraint set: per-point VALU must stay at r6's TPW=16 level AND occupancy
// at 16 waves/CU AND one shared blob. Solution: two waves share one 16-point
// act slice; member m computes output cols m*32..m*32+31 (it = m*2+it2) and
// encodes levels m*12..m*12+11. Work SPLIT not duplicated; LDS = 151.5 KB
// (same as r6) with 1024 threads. Cross-wave visibility within a pair via
// uniform __syncthreads() at each read/write phase boundary.

__device__ __forceinline__ float h2f(u16 b) {
    union { u16 u; _Float16 h; } v; v.u = b; return (float)v.h;
}
__device__ __forceinline__ u16 f2h(float x) {
    union { _Float16 h; u16 u; } v; v.h = (_Float16)x; return v.u;   // RNE v_cvt_f16_f32
}
__device__ __forceinline__ void hsplit(float x, u16& h, u16& l) {
    h = f2h(x);
    float r = x - h2f(h);
    l = f2h(r);
}
__device__ __forceinline__ u32 packhl(float x) {
    u16 h, l; hsplit(x, h, l);
    return ((u32)h << 16) | l;
}
__device__ __forceinline__ float unpackhl(u32 w) {
    return h2f((u16)(w >> 16)) + h2f((u16)(w & 0xffffu));
}
// A&S 7.1.26 erf (|eps|<=1.5e-7), hw rcp + exp2
__device__ __forceinline__ float gelu_f(float x) {
    float z  = fabsf(x) * 0.70710678118654752f;
    float t  = RCPF(fmaf(0.3275911f, z, 1.0f));
    float e  = EXP2F(-z * z * 1.44269504088896340f);
    float p  = fmaf(1.061405429f, t, -1.453152027f);
    p = fmaf(p, t, 1.421413741f);
    p = fmaf(p, t, -0.284496736f);
    p = fmaf(p, t, 0.254829592f);
    p = p * t;
    float erfv = fmaf(-p, e, 1.0f);
    float se   = copysignf(erfv, x);
    return x * fmaf(0.5f, se, 0.5f);
}
__device__ __forceinline__ float sigmoid_f(float y) {
    return RCPF(1.0f + EXP2F(-y * 1.44269504088896340f));
}
__device__ __forceinline__ f16x8 cast8h(u32 a, u32 b, u32 c, u32 d) {
    union { u32 u[4]; f16x8 h; } v; v.u[0]=a; v.u[1]=b; v.u[2]=c; v.u[3]=d; return v.h;
}
__device__ __forceinline__ f16x8 cast8hv(u32x4 u) {
    union { u32x4 u4; f16x8 h; } v; v.u4 = u; return v.h;
}
__device__ __forceinline__ void window_scale(int l, const int* iter, float& sc, float& wl) {
    sc = powf(10.0f, (float)l * (-4.0f / 23.0f));
    double itd = (double)iter[0] / 10000.0;
    itd = itd < 0.0 ? 0.0 : (itd > 1.0 ? 1.0 : itd);
    float tL = (float)((0.3 + 0.7 * itd) * 24.0);
    float arg = fminf(fmaxf(tL - (float)l, 0.0f), 1.0f);
    wl = 0.5f - 0.5f * cosf(3.14159265358979323846f * arg);
}

// corner-parallel partial: lane handles corners c0, c0+1 of one level.
// Calling ISSUES the gathers; caller consumes later (counted-vmcnt pipeline).
__device__ __forceinline__ void hash_level_part(float px, float py, float pz, float sc,
                                                int sx, int sy, int sz, int c0,
                                                const float* __restrict__ tl,
                                                float2& g0, float2& g1, float& w0, float& w1) {
    float cx = px / sc, cy = py / sc, cz = pz / sc;
    float fx = floorf(cx), fy = floorf(cy), fz = floorf(cz);
    float rx = cx - fx, ry = cy - fy, rz = cz - fz;
    int bx = (int)fx + sx, by = (int)fy + sy, bz = (int)fz + sz;
    #pragma unroll
    for (int cc = 0; cc < 2; cc++) {
        int c = c0 + cc;
        u32 hx = (u32)(bx + (c & 1));
        u32 hy = (u32)(by + ((c >> 1) & 1)) * 2654435761u;
        u32 hz = (u32)(bz + ((c >> 2) & 1)) * 805459861u;
        u32 idx = (hx ^ hy ^ hz) & (CAPN - 1);
        float w = ((c & 1) ? rx : 1.0f - rx)
                * ((c & 2) ? ry : 1.0f - ry)
                * ((c & 4) ? rz : 1.0f - rz);
        float2 tf = *(const float2*)(tl + 2 * (size_t)idx);
        if (cc == 0) { g0 = tf; w0 = w; } else { g1 = tf; w1 = w; }
    }
}

// ====== MFMA layer (pair-split): member m computes it = m*2 + {0,1} ======
template <int NKT, bool SHT>
__device__ __forceinline__ void mfma_layer_pair(const u32* blob, const u32* actw,
                                                int lane, int m, f32x4 acc[2]) {
    const int q = lane >> 4, r = lane & 15;
    const int half = NKT * 1024;
    #pragma unroll
    for (int it2 = 0; it2 < 2; it2++) acc[it2] = (f32x4){0.f, 0.f, 0.f, 0.f};
    #pragma unroll
    for (int kt = 0; kt < NKT; kt++) {
        f16x8 whi[2], wlo[2];
        #pragma unroll
        for (int it2 = 0; it2 < 2; it2++) {
            const int it = m * 2 + it2;
            const u32* pb = blob + ((it * NKT + kt) * 64 + lane) * 4;
            whi[it2] = cast8hv(*(const u32x4*)pb);       // ds_read_b128
            wlo[it2] = cast8hv(*(const u32x4*)(pb + half));
        }
        bool zero = SHT && (kt == NKT - 1) && (q >= 2);
        const u32* rowp = actw + r * STR + kt * 32 + q * 8;
        u32x4 v0 = *(const u32x4*)rowp;                  // 16B-aligned (STR=84)
        u32x4 v1 = *(const u32x4*)(rowp + 4);
        if (zero) { v0 = (u32x4){0,0,0,0}; v1 = (u32x4){0,0,0,0}; }
        u32 v[8] = { v0.x, v0.y, v0.z, v0.w, v1.x, v1.y, v1.z, v1.w };
        u32 xh[4], xl[4];
        #pragma unroll
        for (int j2 = 0; j2 < 4; j2++) {
            xh[j2] = (v[2*j2] >> 16) | (v[2*j2+1] & 0xffff0000u);
            xl[j2] = (v[2*j2] & 0xffffu) | (v[2*j2+1] << 16);
        }
        f16x8 bh = cast8h(xh[0], xh[1], xh[2], xh[3]);
        f16x8 bl = cast8h(xl[0], xl[1], xl[2], xl[3]);
        #pragma unroll
        for (int it2 = 0; it2 < 2; it2++) {
            acc[it2] = __builtin_amdgcn_mfma_f32_16x16x32_f16(whi[it2], bh, acc[it2], 0, 0, 0);
            acc[it2] = __builtin_amdgcn_mfma_f32_16x16x32_f16(whi[it2], bl, acc[it2], 0, 0, 0);
            acc[it2] = __builtin_amdgcn_mfma_f32_16x16x32_f16(wlo[it2], bh, acc[it2], 0, 0, 0);
        }
    }
}

__device__ __forceinline__ void epilogue_pair(f32x4 acc[2], const float* __restrict__ bias,
                                              u32* actw, int lane, int m) {
    const int q = lane >> 4, r = lane & 15;
    #pragma unroll
    for (int it2 = 0; it2 < 2; it2++) {
        const int it = m * 2 + it2;
        int mb = it * 16 + q * 4;
        float c0 = bias[mb], c1 = bias[mb + 1], c2 = bias[mb + 2], c3 = bias[mb + 3];
        f32x4 d = acc[it2];
        u32x4 wv;
        // descale 2^-16 (A,B both x256), gelu, re-scale 2^8 for the next layer
        wv.x = packhl(gelu_f(fmaf(d[0], 0x1p-16f, c0)) * 256.0f);
        wv.y = packhl(gelu_f(fmaf(d[1], 0x1p-16f, c1)) * 256.0f);
        wv.z = packhl(gelu_f(fmaf(d[2], 0x1p-16f, c2)) * 256.0f);
        wv.w = packhl(gelu_f(fmaf(d[3], 0x1p-16f, c3)) * 256.0f);
        *(u32x4*)(actw + r * STR + mb) = wv;             // ds_write_b128
    }
}

// ================= persistent kernel: prep weights once, loop over tiles =================
__global__ void __launch_bounds__(1024, 1) nerf_persist(
    const float* __restrict__ pos, const float* __restrict__ dirs,
    const int* __restrict__ iter, const float* __restrict__ tables,
    const int* __restrict__ shifts,
    const float* __restrict__ W1, const float* __restrict__ b1,
    const float* __restrict__ W2, const float* __restrict__ b2,
    const float* __restrict__ W3, const float* __restrict__ b3,
    const float* __restrict__ W4, const float* __restrict__ b4,
    const float* __restrict__ R1, const float* __restrict__ rb1,
    const float* __restrict__ R2, const float* __restrict__ rb2,
    const float* __restrict__ R3, const float* __restrict__ rb3,
    float* __restrict__ out, int n, int nbat)
{
    extern __shared__ u32 lds[];
    const int tid  = threadIdx.x;
    const int lane = tid & 63;
    const int wave = tid >> 6;
    const int pair = wave >> 1;    // 0..7: tile owner
    const int m    = wave & 1;     // pair member: output-col / level half
    const int r = lane & 15;       // point slot within tile
    const int h = lane >> 4;       // quarter index 0..3 (== q)

    // ---- prep: convert all weights into the LDS blob (once per block) ----
    {
        const float* Wp[6] = { W1, W2, W3, W4, R1, R2 };
        for (int e2 = tid; e2 < 13312; e2 += 1024) {
            int p = e2, base, nkt, Ksrc, ldm, coloff, layer;
            if      (p < 2048)  { layer=0; base=WB1;  nkt=2; Ksrc=51; ldm=64; coloff=0; }
            else if (p < 4096)  { layer=1; base=WB2;  nkt=2; Ksrc=64; ldm=64; coloff=0; p-=2048; }
            else if (p < 6144)  { layer=2; base=WB3;  nkt=2; Ksrc=64; ldm=64; coloff=0; p-=4096; }
            else if (p < 8192)  { layer=3; base=WB4;  nkt=2; Ksrc=64; ldm=65; coloff=1; p-=6144; }
            else if (p < 11264) { layer=4; base=WBR1; nkt=3; Ksrc=80; ldm=64; coloff=0; p-=8192; }
            else                { layer=5; base=WBR2; nkt=2; Ksrc=64; ldm=64; coloff=0; p-=11264; }
            const float* W = Wp[layer];
            int j = p & 3, ln = (p >> 2) & 63, fk = p >> 8;
            int qq = ln >> 4, rr = ln & 15;
            int kt = fk % nkt, it = fk / nkt;
            int mm = it * 16 + rr;
            int k0 = kt * 32 + qq * 8 + 2 * j;
            float w0 = (k0     < Ksrc) ? W[(size_t)k0 * ldm + mm + coloff] * 256.0f : 0.0f;
            float w1 = (k0 + 1 < Ksrc) ? W[(size_t)(k0 + 1) * ldm + mm + coloff] * 256.0f : 0.0f;
            u16 h0, l0, h1, l1; hsplit(w0, h0, l0); hsplit(w1, h1, l1);
            int half = nkt * 1024;
            int idx  = base + (fk * 64 + ln) * 4 + j;
            lds[idx]        = (u32)h0 | ((u32)h1 << 16);
            lds[idx + half] = (u32)l0 | ((u32)l1 << 16);
        }
        if (tid < 24) {
            float sc, wl; window_scale(tid, iter, sc, wl);
            lds[SWOFF + 2*tid]     = __float_as_uint(sc);
            lds[SWOFF + 2*tid + 1] = __float_as_uint(wl);
        }
        if (tid >= 64 && tid < 128)  lds[W4C + tid - 64]  = __float_as_uint(W4[(size_t)(tid - 64) * 65]);
        if (tid >= 128 && tid < 320) lds[R3C + tid - 128] = __float_as_uint(R3[tid - 128]);
        if (tid >= 320 && tid < 392) lds[SHF + tid - 320] = (u32)shifts[tid - 320];
    }
    __syncthreads();   // blob/tables ready; read-only hereafter

    u32* actw  = lds + ACT0 + pair * ACTSZ;
    u32* myrow = actw + r * STR;

    for (int bb = blockIdx.x; bb < nbat; bb += gridDim.x) {
        const int tile = bb * NPAIRS + pair;
        const bool tok = ((size_t)tile * TPW < (size_t)n);
        const int i    = tile * TPW + r;
        const bool valid = tok && (i < n);

        float px = 0.f, py = 0.f, pz = 0.f;
        if (valid) { px = pos[3*i]; py = pos[3*i+1]; pz = pos[3*i+2]; }

        if (tok && m == 0 && h == 0) {
            #pragma unroll
            for (int k = 51; k < 64; k++) myrow[k] = 0u;
            myrow[48] = packhl(px * 256.0f);
            myrow[49] = packhl(py * 256.0f);
            myrow[50] = packhl(pz * 256.0f);
        }

        // ---- encode: member m does levels m*12..m*12+11, 4 lanes/pt x 2 corners,
        //      1-deep issue/consume pipeline (r8 technique, no per-level barriers) ----
        const int c0 = h * 2;
        const int lb = m * 12;
        float2 gA0 = {0.f, 0.f}, gA1 = {0.f, 0.f};
        float  wA0 = 0.f, wA1 = 0.f;
        if (tok) {
            float sc = __uint_as_float(lds[SWOFF + 2*lb]);
            hash_level_part(px, py, pz, sc,
                            (int)lds[SHF + 3*lb], (int)lds[SHF + 3*lb + 1],
                            (int)lds[SHF + 3*lb + 2], c0,
                            tables + 2 * ((size_t)lb * CAPN), gA0, gA1, wA0, wA1);
        }
        #pragma unroll
        for (int li = 0; li < 12; li++) {
            const int l = lb + li;
            float2 gB0 = {0.f, 0.f}, gB1 = {0.f, 0.f};
            float  wB0 = 0.f, wB1 = 0.f;
            if (li + 1 < 12 && tok) {
                const int ln = l + 1;
                float scn = __uint_as_float(lds[SWOFF + 2*ln]);
                hash_level_part(px, py, pz, scn,
                                (int)lds[SHF + 3*ln], (int)lds[SHF + 3*ln + 1],
                                (int)lds[SHF + 3*ln + 2], c0,
                                tables + 2 * ((size_t)ln * CAPN), gB0, gB1, wB0, wB1);
            }
            if (tok) {
                float wl = __uint_as_float(lds[SWOFF + 2*l + 1]);
                float a0 = fmaf(wA0, gA0.x, wA1 * gA1.x);
                float a1 = fmaf(wA0, gA0.y, wA1 * gA1.y);
                a0 += __shfl_xor(a0, 16); a0 += __shfl_xor(a0, 32);
                a1 += __shfl_xor(a1, 16); a1 += __shfl_xor(a1, 32);
                if (h == 0) {
                    myrow[2*l]     = (u32)f2h(a0 * wl * 256.0f) << 16;
                    myrow[2*l + 1] = (u32)f2h(a1 * wl * 256.0f) << 16;
                }
            }
            gA0 = gB0; gA1 = gB1; wA0 = wB0; wA1 = wB1;
        }
        __syncthreads();   // pair partner's feature cols visible

        f32x4 acc[2];
        // L1..L3: MFMA reads -> barrier -> epilogue writes -> barrier
        mfma_layer_pair<2, false>(lds + WB1, actw, lane, m, acc);
        __syncthreads();
        epilogue_pair(acc, b1, actw, lane, m);
        __syncthreads();
        mfma_layer_pair<2, false>(lds + WB2, actw, lane, m, acc);
        __syncthreads();
        epilogue_pair(acc, b2, actw, lane, m);
        __syncthreads();
        mfma_layer_pair<2, false>(lds + WB3, actw, lane, m, acc);
        __syncthreads();
        epilogue_pair(acc, b3, actw, lane, m);
        __syncthreads();

        // density dot (reads X3) + W4 MFMA (reads X3) -- both read-only phase
        {
            float t = 0.f;
            #pragma unroll
            for (int kk = 0; kk < 16; kk++) {
                int k = h * 16 + kk;
                t = fmaf(unpackhl(myrow[k]), __uint_as_float(lds[W4C + k]), t);
            }
            t += __shfl_xor(t, 16);
            t += __shfl_xor(t, 32);
            float s = fmaf(t, 0x1p-8f, b4[0]);
            if (m == 0 && h == 0 && valid)
                out[(size_t)3 * n + i] = fmaxf(s, 0.f) + log1pf(expf(-fabsf(s)));
        }
        mfma_layer_pair<2, false>(lds + WB4, actw, lane, m, acc);   // W4 cols 1..64
        __syncthreads();
        epilogue_pair(acc, b4 + 1, actw, lane, m);
        // SH -> feats 64..79 (member 0 writes; cols disjoint from W4's 0..63)
        if (m == 0) {
            float dx = 0.f, dy = 0.f, dz = 0.f;
            if (valid) { dx = dirs[3*i]; dy = dirs[3*i+1]; dz = dirs[3*i+2]; }
            float xx = dx*dx, yy = dy*dy, zz = dz*dz;
            float sh[16];
            sh[0]  = 0.28209479177387814f;
            sh[1]  = -0.48860251190291987f * dy;
            sh[2]  = 0.48860251190291987f * dz;
            sh[3]  = -0.48860251190291987f * dx;
            sh[4]  = 1.0925484305920792f * dx * dy;
            sh[5]  = -1.0925484305920792f * dy * dz;
            sh[6]  = 0.94617469575756f * zz - 0.31539156525252f;
            sh[7]  = -1.0925484305920792f * dx * dz;
            sh[8]  = 0.5462742152960396f * (xx - yy);
            sh[9]  = -0.5900435899266435f * dy * (3.0f * xx - yy);
            sh[10] = 2.890611442640554f * dx * dy * dz;
            sh[11] = -0.4570457994644657f * dy * (4.0f * zz - xx - yy);
            sh[12] = 0.37317633259011546f * dz * (2.0f * zz - 3.0f * xx - 3.0f * yy);
            sh[13] = -0.4570457994644657f * dx * (4.0f * zz - xx - yy);
            sh[14] = 1.445305721320277f * dz * (xx - yy);
            sh[15] = -0.5900435899266435f * dx * (xx - 3.0f * yy);
            if (tok) {
                #pragma unroll
                for (int j = 0; j < 4; j++) myrow[64 + h * 4 + j] = packhl(sh[h * 4 + j] * 256.0f);
            }
        }
        __syncthreads();

        mfma_layer_pair<3, true >(lds + WBR1, actw, lane, m, acc);
        __syncthreads();
        epilogue_pair(acc, rb1, actw, lane, m);
        __syncthreads();
        mfma_layer_pair<2, false>(lds + WBR2, actw, lane, m, acc);
        __syncthreads();
        epilogue_pair(acc, rb2, actw, lane, m);
        __syncthreads();

        // R3 + sigmoid (read-only on act)
        {
            float t0 = 0.f, t1 = 0.f, t2 = 0.f;
            #pragma unroll
            for (int kk = 0; kk < 16; kk++) {
                int k = h * 16 + kk;
                float xv = unpackhl(myrow[k]);
                t0 = fmaf(xv, __uint_as_float(lds[R3C + 3*k + 0]), t0);
                t1 = fmaf(xv, __uint_as_float(lds[R3C + 3*k + 1]), t1);
                t2 = fmaf(xv, __uint_as_float(lds[R3C + 3*k + 2]), t2);
            }
            t0 += __shfl_xor(t0, 16); t0 += __shfl_xor(t0, 32);
            t1 += __shfl_xor(t1, 16); t1 += __shfl_xor(t1, 32);
            t2 += __shfl_xor(t2, 16); t2 += __shfl_xor(t2, 32);
            if (m == 0 && h == 0 && valid) {
                float y0 = fmaf(t0, 0x1p-8f, rb3[0]);
                float y1 = fmaf(t1, 0x1p-8f, rb3[1]);
                float y2 = fmaf(t2, 0x1p-8f, rb3[2]);
                out[(size_t)3 * i + 0] = sigmoid_f(y0);
                out[(size_t)3 * i + 1] = sigmoid_f(y1);
                out[(size_t)3 * i + 2] = sigmoid_f(y2);
            }
        }
        __syncthreads();   // act reads done before next iteration's encode writes
    }
}

extern "C" void kernel_launch(void* const* d_in, const int* in_sizes, int n_in,
                              void* d_out, int out_size, void* d_ws, size_t ws_size,
                              hipStream_t stream) {
    (void)d_ws; (void)ws_size;
    int n = in_sizes[0] / 3;
    int ntiles = (n + TPW - 1) / TPW;
    int nbat = (ntiles + NPAIRS - 1) / NPAIRS;
    int grid = nbat < 256 ? nbat : 256;
    size_t ldsb = (size_t)LDS_U32 * 4;   // 151552 B

    hipFuncSetAttribute(reinterpret_cast<const void*>(nerf_persist),
                        hipFuncAttributeMaxDynamicSharedMemorySize, (int)ldsb);

    nerf_persist<<<grid, 1024, ldsb, stream>>>(
        (const float*)d_in[0], (const float*)d_in[1], (const int*)d_in[2],
        (const float*)d_in[3], (const int*)d_in[4],
        (const float*)d_in[5],  (const float*)d_in[6],
        (const float*)d_in[7],  (const float*)d_in[8],
        (const float*)d_in[9],  (const float*)d_in[10],
        (const float*)d_in[11], (const float*)d_in[12],
        (const float*)d_in[13], (const float*)d_in[14],
        (const float*)d_in[15], (const float*)d_in[16],
        (const float*)d_in[17], (const float*)d_in[18],
        (float*)d_out, n, nbat);
}

// Round 11
// 1043.828 us; speedup vs baseline: 1.8585x; 1.8585x over previous
//
#include <hip/hip_runtime.h>
#include <math.h>

typedef unsigned short u16;
typedef unsigned int   u32;

#define LVLS 24
#define CAPN (1 << 18)
#define STR  84            // act row stride in u32: 336B = 21*16 -> 16B-aligned rows
#define WAVES 8            // waves per block (512 threads)
#define TPW  16            // points per wave tile
#define ACTSZ (TPW * STR + 16)   // 1360 u32 per wave act slice

// ---- LDS layout (u32 offsets) ----
#define WB1   0
#define WB2   4096
#define WB3   8192
#define WB4   12288        /* W4 cols 1..64 */
#define WBR1  16384        /* NKT=3 */
#define WBR2  22528        /* blob end 26624 */
#define SWOFF 26624        /* 24 x {scale, window} floats  -> 48 u32 */
#define W4C   26672        /* W4 column 0 (64 floats) */
#define R3C   26736        /* R3 64x3 floats (192) */
#define SHF   26928        /* shifts 24x3 ints (72) */
#define ACT0  27008        /* 8 wave act slices of ACTSZ */
#define LDS_U32 (ACT0 + WAVES * ACTSZ)   /* 37888 u32 = 151552 B <= 160 KiB */

typedef float    f32x4 __attribute__((ext_vector_type(4)));
typedef _Float16 f16x8 __attribute__((ext_vector_type(8)));
typedef u32      u32x4 __attribute__((ext_vector_type(4)));

#if __has_builtin(__builtin_amdgcn_rcpf)
#define RCPF(x) __builtin_amdgcn_rcpf(x)
#else
#define RCPF(x) (1.0f / (x))
#endif
#if __has_builtin(__builtin_amdgcn_exp2f)
#define EXP2F(x) __builtin_amdgcn_exp2f(x)
#else
#define EXP2F(x) exp2f(x)
#endif

// ---- global scaling scheme (fp16-denormal avoidance; verified abs=3.9e-3) ----
// B side stored as 256*x in fp16 hi/lo; A side (weights) 256*w hi/lo blob in
// LDS; epilogue descales by 2^-16.
//
// r11: two-phase persistent kernel. r5-r10 established: random-gather BW
// ceilings at ~3.1 TB/s regardless of occupancy; dur ~= fetch/3.1TB/s; the
// only remaining lever is FETCH VOLUME. Level-interleaved encode (all prior
// persistent variants) re-fetches each 2MB level table ~10x. Phase 1 here is
// LEVEL-MAJOR: each block encodes ALL its 4096 points for level l before
// l+1 (pos in registers), writing packed fp16 features to pf in d_ws. All
// blocks run identical uniform work -> natural lockstep -> per-XCD footprint
// ~1 table (2MB <= L2): fetch floor ~24x2MBx8 = 0.4GB. Phase 2 = the r6 MLP
// loop reading the block's OWN pf range (no cross-block dep, no grid sync).
// d_ws is written AND read within ONE dispatch -> replay-poison-safe (the
// r1 hazard was cross-dispatch). Fallback (ws too small): r6 inline encode.

__device__ __forceinline__ float h2f(u16 b) {
    union { u16 u; _Float16 h; } v; v.u = b; return (float)v.h;
}
__device__ __forceinline__ u16 f2h(float x) {
    union { _Float16 h; u16 u; } v; v.h = (_Float16)x; return v.u;   // RNE v_cvt_f16_f32
}
__device__ __forceinline__ void hsplit(float x, u16& h, u16& l) {
    h = f2h(x);
    float r = x - h2f(h);
    l = f2h(r);
}
__device__ __forceinline__ u32 packhl(float x) {
    u16 h, l; hsplit(x, h, l);
    return ((u32)h << 16) | l;
}
__device__ __forceinline__ float unpackhl(u32 w) {
    return h2f((u16)(w >> 16)) + h2f((u16)(w & 0xffffu));
}
// A&S 7.1.26 erf (|eps|<=1.5e-7), hw rcp + exp2
__device__ __forceinline__ float gelu_f(float x) {
    float z  = fabsf(x) * 0.70710678118654752f;
    float t  = RCPF(fmaf(0.3275911f, z, 1.0f));
    float e  = EXP2F(-z * z * 1.44269504088896340f);
    float p  = fmaf(1.061405429f, t, -1.453152027f);
    p = fmaf(p, t, 1.421413741f);
    p = fmaf(p, t, -0.284496736f);
    p = fmaf(p, t, 0.254829592f);
    p = p * t;
    float erfv = fmaf(-p, e, 1.0f);
    float se   = copysignf(erfv, x);
    return x * fmaf(0.5f, se, 0.5f);
}
__device__ __forceinline__ float sigmoid_f(float y) {
    return RCPF(1.0f + EXP2F(-y * 1.44269504088896340f));
}
__device__ __forceinline__ f16x8 cast8h(u32 a, u32 b, u32 c, u32 d) {
    union { u32 u[4]; f16x8 h; } v; v.u[0]=a; v.u[1]=b; v.u[2]=c; v.u[3]=d; return v.h;
}
__device__ __forceinline__ f16x8 cast8hv(u32x4 u) {
    union { u32x4 u4; f16x8 h; } v; v.u4 = u; return v.h;
}
__device__ __forceinline__ void window_scale(int l, const int* iter, float& sc, float& wl) {
    sc = powf(10.0f, (float)l * (-4.0f / 23.0f));
    double itd = (double)iter[0] / 10000.0;
    itd = itd < 0.0 ? 0.0 : (itd > 1.0 ? 1.0 : itd);
    float tL = (float)((0.3 + 0.7 * itd) * 24.0);
    float arg = fminf(fmaxf(tL - (float)l, 0.0f), 1.0f);
    wl = 0.5f - 0.5f * cosf(3.14159265358979323846f * arg);
}

// serial 8-corner hash interp (r3-verified ordering) -> f0, f1 (window applied)
__device__ __forceinline__ void hash_level(float px, float py, float pz, float sc, float wl,
                                           int sx, int sy, int sz,
                                           const float* __restrict__ tl,
                                           float& f0, float& f1) {
    float cx = px / sc, cy = py / sc, cz = pz / sc;
    float fx = floorf(cx), fy = floorf(cy), fz = floorf(cz);
    float rx = cx - fx, ry = cy - fy, rz = cz - fz;
    int bx = (int)fx + sx, by = (int)fy + sy, bz = (int)fz + sz;
    u32 hx0 = (u32)bx, hx1 = (u32)(bx + 1);
    u32 hy0 = (u32)by * 2654435761u, hy1 = (u32)(by + 1) * 2654435761u;
    u32 hz0 = (u32)bz * 805459861u,  hz1 = (u32)(bz + 1) * 805459861u;
    float a0 = 0.f, a1 = 0.f;
    #pragma unroll
    for (int c = 0; c < 8; c++) {
        u32 hx = (c & 1) ? hx1 : hx0;
        u32 hy = (c & 2) ? hy1 : hy0;
        u32 hz = (c & 4) ? hz1 : hz0;
        u32 idx = (hx ^ hy ^ hz) & (CAPN - 1);
        float w = ((c & 1) ? rx : 1.0f - rx);
        w *= ((c & 2) ? ry : 1.0f - ry);
        w *= ((c & 4) ? rz : 1.0f - rz);
        float2 tf = *(const float2*)(tl + 2 * (size_t)idx);
        a0 = fmaf(w, tf.x, a0);
        a1 = fmaf(w, tf.y, a1);
    }
    f0 = a0 * wl;
    f1 = a1 * wl;
}

// corner-parallel partial for the fallback path (r6-verified)
__device__ __forceinline__ void hash_level_part(float px, float py, float pz, float sc,
                                                int sx, int sy, int sz, int c0,
                                                const float* __restrict__ tl,
                                                float2& g0, float2& g1, float& w0, float& w1) {
    float cx = px / sc, cy = py / sc, cz = pz / sc;
    float fx = floorf(cx), fy = floorf(cy), fz = floorf(cz);
    float rx = cx - fx, ry = cy - fy, rz = cz - fz;
    int bx = (int)fx + sx, by = (int)fy + sy, bz = (int)fz + sz;
    #pragma unroll
    for (int cc = 0; cc < 2; cc++) {
        int c = c0 + cc;
        u32 hx = (u32)(bx + (c & 1));
        u32 hy = (u32)(by + ((c >> 1) & 1)) * 2654435761u;
        u32 hz = (u32)(bz + ((c >> 2) & 1)) * 805459861u;
        u32 idx = (hx ^ hy ^ hz) & (CAPN - 1);
        float w = ((c & 1) ? rx : 1.0f - rx)
                * ((c & 2) ? ry : 1.0f - ry)
                * ((c & 4) ? rz : 1.0f - rz);
        float2 tf = *(const float2*)(tl + 2 * (size_t)idx);
        if (cc == 0) { g0 = tf; w0 = w; } else { g1 = tf; w1 = w; }
    }
}

// intra-wave LDS ordering fence (act slices are wave-private)
__device__ __forceinline__ void wavesync() {
    asm volatile("s_waitcnt lgkmcnt(0)" ::: "memory");
    __builtin_amdgcn_sched_barrier(0);
}

// ============ MFMA layer: weights from LDS blob (hi/lo), 16-pt tile ============
template <int NKT, bool SHT>
__device__ __forceinline__ void mfma_layer_lds(const u32* blob, const u32* actw,
                                               int lane, f32x4 acc[4]) {
    const int q = lane >> 4, r = lane & 15;
    const int half = NKT * 1024;
    #pragma unroll
    for (int it = 0; it < 4; it++) acc[it] = (f32x4){0.f, 0.f, 0.f, 0.f};
    #pragma unroll
    for (int kt = 0; kt < NKT; kt++) {
        f16x8 whi[4], wlo[4];
        #pragma unroll
        for (int it = 0; it < 4; it++) {
            const u32* pb = blob + ((it * NKT + kt) * 64 + lane) * 4;
            whi[it] = cast8hv(*(const u32x4*)pb);        // ds_read_b128, dense
            wlo[it] = cast8hv(*(const u32x4*)(pb + half));
        }
        bool zero = SHT && (kt == NKT - 1) && (q >= 2);
        const u32* rowp = actw + r * STR + kt * 32 + q * 8;
        u32x4 v0 = *(const u32x4*)rowp;                  // 16B-aligned (STR=84)
        u32x4 v1 = *(const u32x4*)(rowp + 4);
        if (zero) { v0 = (u32x4){0,0,0,0}; v1 = (u32x4){0,0,0,0}; }
        u32 v[8] = { v0.x, v0.y, v0.z, v0.w, v1.x, v1.y, v1.z, v1.w };
        u32 xh[4], xl[4];
        #pragma unroll
        for (int j2 = 0; j2 < 4; j2++) {
            xh[j2] = (v[2*j2] >> 16) | (v[2*j2+1] & 0xffff0000u);
            xl[j2] = (v[2*j2] & 0xffffu) | (v[2*j2+1] << 16);
        }
        f16x8 bh = cast8h(xh[0], xh[1], xh[2], xh[3]);
        f16x8 bl = cast8h(xl[0], xl[1], xl[2], xl[3]);
        #pragma unroll
        for (int it = 0; it < 4; it++) {
            acc[it] = __builtin_amdgcn_mfma_f32_16x16x32_f16(whi[it], bh, acc[it], 0, 0, 0);
            acc[it] = __builtin_amdgcn_mfma_f32_16x16x32_f16(whi[it], bl, acc[it], 0, 0, 0);
            acc[it] = __builtin_amdgcn_mfma_f32_16x16x32_f16(wlo[it], bh, acc[it], 0, 0, 0);
        }
    }
}

__device__ __forceinline__ void epilogue_gelu(f32x4 acc[4], const float* __restrict__ bias,
                                              u32* actw, int lane) {
    const int q = lane >> 4, r = lane & 15;
    #pragma unroll
    for (int it = 0; it < 4; it++) {
        int mb = it * 16 + q * 4;
        float c0 = bias[mb], c1 = bias[mb + 1], c2 = bias[mb + 2], c3 = bias[mb + 3];
        f32x4 d = acc[it];
        u32x4 wv;
        // descale 2^-16 (A,B both x256), gelu, re-scale 2^8 for the next layer
        wv.x = packhl(gelu_f(fmaf(d[0], 0x1p-16f, c0)) * 256.0f);
        wv.y = packhl(gelu_f(fmaf(d[1], 0x1p-16f, c1)) * 256.0f);
        wv.z = packhl(gelu_f(fmaf(d[2], 0x1p-16f, c2)) * 256.0f);
        wv.w = packhl(gelu_f(fmaf(d[3], 0x1p-16f, c3)) * 256.0f);
        *(u32x4*)(actw + r * STR + mb) = wv;             // ds_write_b128
    }
}

// ================= persistent kernel =================
// SPLIT=true : phase 1 level-major encode -> pf (d_ws), phase 2 MLP from pf.
// SPLIT=false: r6 inline-encode fallback (ws too small).
template <bool SPLIT>
__global__ void __launch_bounds__(512, 1) nerf_persist(
    const float* __restrict__ pos, const float* __restrict__ dirs,
    const int* __restrict__ iter, const float* __restrict__ tables,
    const int* __restrict__ shifts,
    const float* __restrict__ W1, const float* __restrict__ b1,
    const float* __restrict__ W2, const float* __restrict__ b2,
    const float* __restrict__ W3, const float* __restrict__ b3,
    const float* __restrict__ W4, const float* __restrict__ b4,
    const float* __restrict__ R1, const float* __restrict__ rb1,
    const float* __restrict__ R2, const float* __restrict__ rb2,
    const float* __restrict__ R3, const float* __restrict__ rb3,
    u32* __restrict__ pf,
    float* __restrict__ out, int n, int nbat, int ppb)
{
    extern __shared__ u32 lds[];
    const int tid  = threadIdx.x;
    const int lane = tid & 63;
    const int wave = tid >> 6;
    const int r = lane & 15;       // point slot within wave tile
    const int h = lane >> 4;       // quarter index 0..3 (== q)

    // ---- prep: convert all weights into the LDS blob (once per block) ----
    {
        const float* Wp[6] = { W1, W2, W3, W4, R1, R2 };
        for (int e2 = tid; e2 < 13312; e2 += 512) {
            int p = e2, base, nkt, Ksrc, ldm, coloff, layer;
            if      (p < 2048)  { layer=0; base=WB1;  nkt=2; Ksrc=51; ldm=64; coloff=0; }
            else if (p < 4096)  { layer=1; base=WB2;  nkt=2; Ksrc=64; ldm=64; coloff=0; p-=2048; }
            else if (p < 6144)  { layer=2; base=WB3;  nkt=2; Ksrc=64; ldm=64; coloff=0; p-=4096; }
            else if (p < 8192)  { layer=3; base=WB4;  nkt=2; Ksrc=64; ldm=65; coloff=1; p-=6144; }
            else if (p < 11264) { layer=4; base=WBR1; nkt=3; Ksrc=80; ldm=64; coloff=0; p-=8192; }
            else                { layer=5; base=WBR2; nkt=2; Ksrc=64; ldm=64; coloff=0; p-=11264; }
            const float* W = Wp[layer];
            int j = p & 3, ln = (p >> 2) & 63, fk = p >> 8;
            int qq = ln >> 4, rr = ln & 15;
            int kt = fk % nkt, it = fk / nkt;
            int m  = it * 16 + rr;
            int k0 = kt * 32 + qq * 8 + 2 * j;
            float w0 = (k0     < Ksrc) ? W[(size_t)k0 * ldm + m + coloff] * 256.0f : 0.0f;
            float w1 = (k0 + 1 < Ksrc) ? W[(size_t)(k0 + 1) * ldm + m + coloff] * 256.0f : 0.0f;
            u16 h0, l0, h1, l1; hsplit(w0, h0, l0); hsplit(w1, h1, l1);
            int half = nkt * 1024;
            int idx  = base + (fk * 64 + ln) * 4 + j;
            lds[idx]        = (u32)h0 | ((u32)h1 << 16);
            lds[idx + half] = (u32)l0 | ((u32)l1 << 16);
        }
        if (tid < 24) {
            float sc, wl; window_scale(tid, iter, sc, wl);
            lds[SWOFF + 2*tid]     = __float_as_uint(sc);
            lds[SWOFF + 2*tid + 1] = __float_as_uint(wl);
        }
        if (tid >= 64 && tid < 128)  lds[W4C + tid - 64]  = __float_as_uint(W4[(size_t)(tid - 64) * 65]);
        if (tid >= 128 && tid < 320) lds[R3C + tid - 128] = __float_as_uint(R3[tid - 128]);
        if (tid >= 320 && tid < 392) lds[SHF + tid - 320] = (u32)shifts[tid - 320];
    }
    __syncthreads();   // blob/tables ready; read-only hereafter

    u32* actw  = lds + ACT0 + wave * ACTSZ;
    u32* myrow = actw + r * STR;

    const int pbase = SPLIT ? blockIdx.x * ppb : 0;

    if constexpr (SPLIT) {
        // ---- phase 1: LEVEL-MAJOR encode of this block's points into pf ----
        for (int cp = 0; cp < ppb; cp += 512 * 8) {
            float lx[8], ly[8], lz[8];
            bool  lv[8];
            #pragma unroll
            for (int j = 0; j < 8; j++) {
                int off = cp + j * 512 + tid;
                int p = pbase + off;
                lv[j] = (off < ppb) && (p < n);
                lx[j] = 0.f; ly[j] = 0.f; lz[j] = 0.f;
                if (lv[j]) { lx[j] = pos[3*p]; ly[j] = pos[3*p+1]; lz[j] = pos[3*p+2]; }
            }
            for (int l = 0; l < LVLS; l++) {
                float sc = __uint_as_float(lds[SWOFF + 2*l]);
                float wl = __uint_as_float(lds[SWOFF + 2*l + 1]);
                int sx = (int)lds[SHF + 3*l], sy = (int)lds[SHF + 3*l + 1], sz = (int)lds[SHF + 3*l + 2];
                const float* tl = tables + 2 * ((size_t)l * CAPN);
                #pragma unroll 2
                for (int j = 0; j < 8; j++) {
                    if (!lv[j]) continue;
                    float f0, f1;
                    hash_level(lx[j], ly[j], lz[j], sc, wl, sx, sy, sz, tl, f0, f1);
                    int p = pbase + cp + j * 512 + tid;
                    pf[(size_t)l * n + p] = (u32)f2h(f0 * 256.0f) | ((u32)f2h(f1 * 256.0f) << 16);
                }
                __syncthreads();   // keep the block's 8 waves level-aligned
            }
        }
        __syncthreads();           // pf complete for this block's range
    }

    const int iters = SPLIT ? (ppb / (WAVES * TPW)) : nbat;
    for (int bb0 = 0; bb0 < iters; bb0++) {
        int tstart;
        if constexpr (SPLIT) {
            tstart = pbase + (bb0 * WAVES + wave) * TPW;
        } else {
            int bb = blockIdx.x + bb0 * gridDim.x;
            if (bb >= nbat) break;
            tstart = (bb * WAVES + wave) * TPW;
        }
        const bool tok = (tstart < n);
        const int i    = tstart + r;
        const bool valid = tok && (i < n);

        float px = 0.f, py = 0.f, pz = 0.f;
        if (valid) { px = pos[3*i]; py = pos[3*i+1]; pz = pos[3*i+2]; }

        if (tok && h == 0) {
            #pragma unroll
            for (int k = 51; k < 64; k++) myrow[k] = 0u;
            myrow[48] = packhl(px * 256.0f);
            myrow[49] = packhl(py * 256.0f);
            myrow[50] = packhl(pz * 256.0f);
        }

        if constexpr (SPLIT) {
            // features from pf: each lane loads 6 levels for its point
            if (tok) {
                #pragma unroll
                for (int li = 0; li < 6; li++) {
                    int l = h * 6 + li;
                    u32 v = valid ? pf[(size_t)l * n + i] : 0u;
                    myrow[2*l]     = v << 16;           // f0 hi, lo=0
                    myrow[2*l + 1] = v & 0xffff0000u;   // f1 hi, lo=0
                }
            }
        } else {
            // fallback: r6 inline encode (4 lanes/pt x 2 corners, shfl reduce)
            if (tok) {
                const int c0 = h * 2;
                #pragma unroll 2
                for (int l = 0; l < LVLS; l++) {
                    float sc = __uint_as_float(lds[SWOFF + 2*l]);
                    float wl = __uint_as_float(lds[SWOFF + 2*l + 1]);
                    int sx = (int)lds[SHF + 3*l], sy = (int)lds[SHF + 3*l + 1], sz = (int)lds[SHF + 3*l + 2];
                    float2 g0, g1; float w0, w1;
                    hash_level_part(px, py, pz, sc, sx, sy, sz, c0,
                                    tables + 2 * ((size_t)l * CAPN), g0, g1, w0, w1);
                    float a0 = fmaf(w0, g0.x, w1 * g1.x);
                    float a1 = fmaf(w0, g0.y, w1 * g1.y);
                    a0 += __shfl_xor(a0, 16); a0 += __shfl_xor(a0, 32);
                    a1 += __shfl_xor(a1, 16); a1 += __shfl_xor(a1, 32);
                    if (h == 0) {
                        myrow[2*l]     = (u32)f2h(a0 * wl * 256.0f) << 16;
                        myrow[2*l + 1] = (u32)f2h(a1 * wl * 256.0f) << 16;
                    }
                }
            }
        }
        wavesync();

        f32x4 acc[4];
        if (tok) { mfma_layer_lds<2, false>(lds + WB1, actw, lane, acc); epilogue_gelu(acc, b1, actw, lane); }
        wavesync();
        if (tok) { mfma_layer_lds<2, false>(lds + WB2, actw, lane, acc); epilogue_gelu(acc, b2, actw, lane); }
        wavesync();
        if (tok) { mfma_layer_lds<2, false>(lds + WB3, actw, lane, acc); epilogue_gelu(acc, b3, actw, lane); }
        wavesync();

        if (tok) {
            // density: k-split across quarters, combine via shfl_xor(16,32)
            float t = 0.f;
            #pragma unroll
            for (int kk = 0; kk < 16; kk++) {
                int k = h * 16 + kk;
                t = fmaf(unpackhl(myrow[k]), __uint_as_float(lds[W4C + k]), t);
            }
            t += __shfl_xor(t, 16);
            t += __shfl_xor(t, 32);
            float s = fmaf(t, 0x1p-8f, b4[0]);
            if (h == 0 && valid) out[(size_t)3 * n + i] = fmaxf(s, 0.f) + log1pf(expf(-fabsf(s)));

            mfma_layer_lds<2, false>(lds + WB4, actw, lane, acc);   // W4 cols 1..64
            epilogue_gelu(acc, b4 + 1, actw, lane);

            // SH -> feats 64..79 (stored x256); each quarter writes 4 cols
            float dx = 0.f, dy = 0.f, dz = 0.f;
            if (valid) { dx = dirs[3*i]; dy = dirs[3*i+1]; dz = dirs[3*i+2]; }
            float xx = dx*dx, yy = dy*dy, zz = dz*dz;
            float sh[16];
            sh[0]  = 0.28209479177387814f;
            sh[1]  = -0.48860251190291987f * dy;
            sh[2]  = 0.48860251190291987f * dz;
            sh[3]  = -0.48860251190291987f * dx;
            sh[4]  = 1.0925484305920792f * dx * dy;
            sh[5]  = -1.0925484305920792f * dy * dz;
            sh[6]  = 0.94617469575756f * zz - 0.31539156525252f;
            sh[7]  = -1.0925484305920792f * dx * dz;
            sh[8]  = 0.5462742152960396f * (xx - yy);
            sh[9]  = -0.5900435899266435f * dy * (3.0f * xx - yy);
            sh[10] = 2.890611442640554f * dx * dy * dz;
            sh[11] = -0.4570457994644657f * dy * (4.0f * zz - xx - yy);
            sh[12] = 0.37317633259011546f * dz * (2.0f * zz - 3.0f * xx - 3.0f * yy);
            sh[13] = -0.4570457994644657f * dx * (4.0f * zz - xx - yy);
            sh[14] = 1.445305721320277f * dz * (xx - yy);
            sh[15] = -0.5900435899266435f * dx * (xx - 3.0f * yy);
            #pragma unroll
            for (int j = 0; j < 4; j++) myrow[64 + h * 4 + j] = packhl(sh[h * 4 + j] * 256.0f);
        }
        wavesync();

        if (tok) { mfma_layer_lds<3, true >(lds + WBR1, actw, lane, acc); epilogue_gelu(acc, rb1, actw, lane); }
        wavesync();
        if (tok) { mfma_layer_lds<2, false>(lds + WBR2, actw, lane, acc); epilogue_gelu(acc, rb2, actw, lane); }
        wavesync();

        if (tok) {
            // R3 + sigmoid: k-split across quarters
            float t0 = 0.f, t1 = 0.f, t2 = 0.f;
            #pragma unroll
            for (int kk = 0; kk < 16; kk++) {
                int k = h * 16 + kk;
                float xv = unpackhl(myrow[k]);
                t0 = fmaf(xv, __uint_as_float(lds[R3C + 3*k + 0]), t0);
                t1 = fmaf(xv, __uint_as_float(lds[R3C + 3*k + 1]), t1);
                t2 = fmaf(xv, __uint_as_float(lds[R3C + 3*k + 2]), t2);
            }
            t0 += __shfl_xor(t0, 16); t0 += __shfl_xor(t0, 32);
            t1 += __shfl_xor(t1, 16); t1 += __shfl_xor(t1, 32);
            t2 += __shfl_xor(t2, 16); t2 += __shfl_xor(t2, 32);
            if (h == 0 && valid) {
                float y0 = fmaf(t0, 0x1p-8f, rb3[0]);
                float y1 = fmaf(t1, 0x1p-8f, rb3[1]);
                float y2 = fmaf(t2, 0x1p-8f, rb3[2]);
                out[(size_t)3 * i + 0] = sigmoid_f(y0);
                out[(size_t)3 * i + 1] = sigmoid_f(y1);
                out[(size_t)3 * i + 2] = sigmoid_f(y2);
            }
        }
        wavesync();
    }
}

extern "C" void kernel_launch(void* const* d_in, const int* in_sizes, int n_in,
                              void* d_out, int out_size, void* d_ws, size_t ws_size,
                              hipStream_t stream) {
    int n = in_sizes[0] / 3;
    int ntiles = (n + TPW - 1) / TPW;
    int nbat = (ntiles + WAVES - 1) / WAVES;
    size_t ldsb = (size_t)LDS_U32 * 4;   // 151552 B

    size_t need = (size_t)LVLS * (size_t)n * 4;
    bool split = (ws_size >= need) && (n >= 256 * WAVES * TPW);

    if (split) {
        int cpb = (n + 255) / 256;                              // points per block (raw)
        int ppb = (cpb + WAVES * TPW - 1) & ~(WAVES * TPW - 1); // round up to 128
        hipFuncSetAttribute(reinterpret_cast<const void*>(nerf_persist<true>),
                            hipFuncAttributeMaxDynamicSharedMemorySize, (int)ldsb);
        nerf_persist<true><<<256, 512, ldsb, stream>>>(
            (const float*)d_in[0], (const float*)d_in[1], (const int*)d_in[2],
            (const float*)d_in[3], (const int*)d_in[4],
            (const float*)d_in[5],  (const float*)d_in[6],
            (const float*)d_in[7],  (const float*)d_in[8],
            (const float*)d_in[9],  (const float*)d_in[10],
            (const float*)d_in[11], (const float*)d_in[12],
            (const float*)d_in[13], (const float*)d_in[14],
            (const float*)d_in[15], (const float*)d_in[16],
            (const float*)d_in[17], (const float*)d_in[18],
            (u32*)d_ws, (float*)d_out, n, nbat, ppb);
    } else {
        int grid = nbat < 256 ? nbat : 256;
        hipFuncSetAttribute(reinterpret_cast<const void*>(nerf_persist<false>),
                            hipFuncAttributeMaxDynamicSharedMemorySize, (int)ldsb);
        nerf_persist<false><<<grid, 512, ldsb, stream>>>(
            (const float*)d_in[0], (const float*)d_in[1], (const int*)d_in[2],
            (const float*)d_in[3], (const int*)d_in[4],
            (const float*)d_in[5],  (const float*)d_in[6],
            (const float*)d_in[7],  (const float*)d_in[8],
            (const float*)d_in[9],  (const float*)d_in[10],
            (const float*)d_in[11], (const float*)d_in[12],
            (const float*)d_in[13], (const float*)d_in[14],
            (const float*)d_in[15], (const float*)d_in[16],
            (const float*)d_in[17], (const float*)d_in[18],
            (u32*)d_ws, (float*)d_out, n, nbat, 0);
    }
}

// Round 13
// 1021.873 us; speedup vs baseline: 1.8984x; 1.0215x over previous
//
#include <hip/hip_runtime.h>
#include <math.h>

typedef unsigned short u16;
typedef unsigned int   u32;

#define LVLS 24
#define CAPN (1 << 18)
#define WAVES 16           // 1024-thread block = 16 waves = 4/SIMD
#define TPW  16            // points per wave tile

// ---- LDS layout (u32 offsets): weight blob + tables ONLY (no act storage) ----
#define WB1   0
#define WB2   4096
#define WB3   8192
#define WB4   12288        /* W4 cols 1..64 */
#define WBR1  16384        /* NKT=3 */
#define WBR2  22528        /* blob end 26624 */
#define SWOFF 26624        /* 24 x {scale, window} floats */
#define W4C   26672        /* W4 column 0 (64 floats) */
#define R3C   26736        /* R3 64x3 floats */
#define SHF   26928        /* shifts 24x3 ints */
#define LDS_U32 27008      /* 108032 B -> 16 waves/CU fit */

typedef float    f32x4 __attribute__((ext_vector_type(4)));
typedef _Float16 f16x8 __attribute__((ext_vector_type(8)));
typedef u32      u32x4 __attribute__((ext_vector_type(4)));

#if __has_builtin(__builtin_amdgcn_rcpf)
#define RCPF(x) __builtin_amdgcn_rcpf(x)
#else
#define RCPF(x) (1.0f / (x))
#endif
#if __has_builtin(__builtin_amdgcn_exp2f)
#define EXP2F(x) __builtin_amdgcn_exp2f(x)
#else
#define EXP2F(x) exp2f(x)
#endif

// ---- global scaling scheme (fp16-denormal avoidance; verified abs=3.9e-3) ----
// B side (acts) as 256*x fp16 hi/lo packhl u32; A side (weights) 256*w hi/lo
// blob in LDS; epilogue descales 2^-16.
//
// r12 (resubmitted after infra failure): REGISTER-RESIDENT activation chain.
// r11 counters: fetch solved (0.2GB), nothing saturated, occupancy pinned
// 22.5% by 151KB LDS (104KB blob + 43.5KB act slices). The act slices exist
// only to permute 16 features/lane between epilogue layout E[it][j] (feature
// it*16+q*4+j of point r) and B-fragment layout v[e]=feature kt*32+q*8+e.
// That permutation is E[2kt+(q>>1)][e&3] from lane (2(q&1)+(e>>2))*16+r --
// a fixed 4-lane shuffle (16 shfl + 8 sel per kt). Acts stay in regs;
// LDS = 108KB -> 1024-thread block, 16 waves/CU (2x), phase 2 barrier-free.
// Operand bits identical to r11; dot-reduction order changes only (~1e-7).

__device__ __forceinline__ float h2f(u16 b) {
    union { u16 u; _Float16 h; } v; v.u = b; return (float)v.h;
}
__device__ __forceinline__ u16 f2h(float x) {
    union { _Float16 h; u16 u; } v; v.h = (_Float16)x; return v.u;   // RNE v_cvt_f16_f32
}
__device__ __forceinline__ void hsplit(float x, u16& h, u16& l) {
    h = f2h(x);
    float r = x - h2f(h);
    l = f2h(r);
}
__device__ __forceinline__ u32 packhl(float x) {
    u16 h, l; hsplit(x, h, l);
    return ((u32)h << 16) | l;
}
__device__ __forceinline__ float unpackhl(u32 w) {
    return h2f((u16)(w >> 16)) + h2f((u16)(w & 0xffffu));
}
// A&S 7.1.26 erf (|eps|<=1.5e-7), hw rcp + exp2
__device__ __forceinline__ float gelu_f(float x) {
    float z  = fabsf(x) * 0.70710678118654752f;
    float t  = RCPF(fmaf(0.3275911f, z, 1.0f));
    float e  = EXP2F(-z * z * 1.44269504088896340f);
    float p  = fmaf(1.061405429f, t, -1.453152027f);
    p = fmaf(p, t, 1.421413741f);
    p = fmaf(p, t, -0.284496736f);
    p = fmaf(p, t, 0.254829592f);
    p = p * t;
    float erfv = fmaf(-p, e, 1.0f);
    float se   = copysignf(erfv, x);
    return x * fmaf(0.5f, se, 0.5f);
}
__device__ __forceinline__ float sigmoid_f(float y) {
    return RCPF(1.0f + EXP2F(-y * 1.44269504088896340f));
}
__device__ __forceinline__ f16x8 cast8h(u32 a, u32 b, u32 c, u32 d) {
    union { u32 u[4]; f16x8 h; } v; v.u[0]=a; v.u[1]=b; v.u[2]=c; v.u[3]=d; return v.h;
}
__device__ __forceinline__ f16x8 cast8hv(u32x4 u) {
    union { u32x4 u4; f16x8 h; } v; v.u4 = u; return v.h;
}
__device__ __forceinline__ void window_scale(int l, const int* iter, float& sc, float& wl) {
    sc = powf(10.0f, (float)l * (-4.0f / 23.0f));
    double itd = (double)iter[0] / 10000.0;
    itd = itd < 0.0 ? 0.0 : (itd > 1.0 ? 1.0 : itd);
    float tL = (float)((0.3 + 0.7 * itd) * 24.0);
    float arg = fminf(fmaxf(tL - (float)l, 0.0f), 1.0f);
    wl = 0.5f - 0.5f * cosf(3.14159265358979323846f * arg);
}

// serial 8-corner hash interp (r3-verified ordering) -> f0, f1 (window applied)
__device__ __forceinline__ void hash_level(float px, float py, float pz, float sc, float wl,
                                           int sx, int sy, int sz,
                                           const float* __restrict__ tl,
                                           float& f0, float& f1) {
    float cx = px / sc, cy = py / sc, cz = pz / sc;
    float fx = floorf(cx), fy = floorf(cy), fz = floorf(cz);
    float rx = cx - fx, ry = cy - fy, rz = cz - fz;
    int bx = (int)fx + sx, by = (int)fy + sy, bz = (int)fz + sz;
    u32 hx0 = (u32)bx, hx1 = (u32)(bx + 1);
    u32 hy0 = (u32)by * 2654435761u, hy1 = (u32)(by + 1) * 2654435761u;
    u32 hz0 = (u32)bz * 805459861u,  hz1 = (u32)(bz + 1) * 805459861u;
    float a0 = 0.f, a1 = 0.f;
    #pragma unroll
    for (int c = 0; c < 8; c++) {
        u32 hx = (c & 1) ? hx1 : hx0;
        u32 hy = (c & 2) ? hy1 : hy0;
        u32 hz = (c & 4) ? hz1 : hz0;
        u32 idx = (hx ^ hy ^ hz) & (CAPN - 1);
        float w = ((c & 1) ? rx : 1.0f - rx);
        w *= ((c & 2) ? ry : 1.0f - ry);
        w *= ((c & 4) ? rz : 1.0f - rz);
        float2 tf = *(const float2*)(tl + 2 * (size_t)idx);
        a0 = fmaf(w, tf.x, a0);
        a1 = fmaf(w, tf.y, a1);
    }
    f0 = a0 * wl;
    f1 = a1 * wl;
}

// ====== MFMA layer, register acts: B-fragment via 4-lane shuffle exchange ======
// E[it][j] = packhl feature (it*16 + q*4 + j) of point r, held by lane q*16+r.
// v[e] for (kt) = E[2kt+(q>>1)][e&3] pulled from lane (2(q&1)+(e>>2))*16+r.
template <int NKT>
__device__ __forceinline__ void mfma_layer_reg(const u32* blob, const u32 E[6][4],
                                               int lane, f32x4 acc[4]) {
    const int q = lane >> 4, r = lane & 15;
    const int half = NKT * 1024;
    const int src0 = ((q & 1) << 5) + r;   // lane of q_s = 2(q&1)
    const int src1 = src0 + 16;            // lane of q_s = 2(q&1)+1
    const bool hiq = (q >= 2);
    #pragma unroll
    for (int it = 0; it < 4; it++) acc[it] = (f32x4){0.f, 0.f, 0.f, 0.f};
    #pragma unroll
    for (int kt = 0; kt < NKT; kt++) {
        f16x8 whi[4], wlo[4];
        #pragma unroll
        for (int it = 0; it < 4; it++) {
            const u32* pb = blob + ((it * NKT + kt) * 64 + lane) * 4;
            whi[it] = cast8hv(*(const u32x4*)pb);        // ds_read_b128
            wlo[it] = cast8hv(*(const u32x4*)(pb + half));
        }
        u32 v[8];
        #pragma unroll
        for (int j = 0; j < 4; j++) {
            u32 a0 = (u32)__shfl((int)E[2*kt][j],     src0);
            u32 a1 = (u32)__shfl((int)E[2*kt + 1][j], src0);
            u32 b0 = (u32)__shfl((int)E[2*kt][j],     src1);
            u32 b1 = (u32)__shfl((int)E[2*kt + 1][j], src1);
            v[j]     = hiq ? a1 : a0;
            v[j + 4] = hiq ? b1 : b0;
        }
        u32 xh[4], xl[4];
        #pragma unroll
        for (int j2 = 0; j2 < 4; j2++) {
            xh[j2] = (v[2*j2] >> 16) | (v[2*j2+1] & 0xffff0000u);
            xl[j2] = (v[2*j2] & 0xffffu) | (v[2*j2+1] << 16);
        }
        f16x8 bh = cast8h(xh[0], xh[1], xh[2], xh[3]);
        f16x8 bl = cast8h(xl[0], xl[1], xl[2], xl[3]);
        #pragma unroll
        for (int it = 0; it < 4; it++) {
            acc[it] = __builtin_amdgcn_mfma_f32_16x16x32_f16(whi[it], bh, acc[it], 0, 0, 0);
            acc[it] = __builtin_amdgcn_mfma_f32_16x16x32_f16(whi[it], bl, acc[it], 0, 0, 0);
            acc[it] = __builtin_amdgcn_mfma_f32_16x16x32_f16(wlo[it], bh, acc[it], 0, 0, 0);
        }
    }
}

// epilogue into registers: E[it][j] <- packhl(gelu(acc*2^-16 + bias)*256)
__device__ __forceinline__ void epilogue_reg(f32x4 acc[4], const float* __restrict__ bias,
                                             int lane, u32 E[6][4]) {
    const int q = lane >> 4;
    #pragma unroll
    for (int it = 0; it < 4; it++) {
        int mb = it * 16 + q * 4;
        float c0 = bias[mb], c1 = bias[mb + 1], c2 = bias[mb + 2], c3 = bias[mb + 3];
        f32x4 d = acc[it];
        E[it][0] = packhl(gelu_f(fmaf(d[0], 0x1p-16f, c0)) * 256.0f);
        E[it][1] = packhl(gelu_f(fmaf(d[1], 0x1p-16f, c1)) * 256.0f);
        E[it][2] = packhl(gelu_f(fmaf(d[2], 0x1p-16f, c2)) * 256.0f);
        E[it][3] = packhl(gelu_f(fmaf(d[3], 0x1p-16f, c3)) * 256.0f);
    }
}

// ================= persistent kernel =================
// SPLIT=true : phase 1 level-major encode -> pf (d_ws, intra-dispatch), phase 2 MLP.
// SPLIT=false: per-lane serial inline encode fallback.
template <bool SPLIT>
__global__ void __launch_bounds__(1024) nerf_persist(
    const float* __restrict__ pos, const float* __restrict__ dirs,
    const int* __restrict__ iter, const float* __restrict__ tables,
    const int* __restrict__ shifts,
    const float* __restrict__ W1, const float* __restrict__ b1,
    const float* __restrict__ W2, const float* __restrict__ b2,
    const float* __restrict__ W3, const float* __restrict__ b3,
    const float* __restrict__ W4, const float* __restrict__ b4,
    const float* __restrict__ R1, const float* __restrict__ rb1,
    const float* __restrict__ R2, const float* __restrict__ rb2,
    const float* __restrict__ R3, const float* __restrict__ rb3,
    u32* __restrict__ pf,
    float* __restrict__ out, int n, int nbat, int ppb)
{
    extern __shared__ u32 lds[];
    const int tid  = threadIdx.x;
    const int lane = tid & 63;
    const int wave = tid >> 6;
    const int r = lane & 15;       // point slot within wave tile
    const int q = lane >> 4;       // quarter 0..3

    // ---- prep: convert all weights into the LDS blob (once per block) ----
    {
        const float* Wp[6] = { W1, W2, W3, W4, R1, R2 };
        for (int e2 = tid; e2 < 13312; e2 += 1024) {
            int p = e2, base, nkt, Ksrc, ldm, coloff, layer;
            if      (p < 2048)  { layer=0; base=WB1;  nkt=2; Ksrc=51; ldm=64; coloff=0; }
            else if (p < 4096)  { layer=1; base=WB2;  nkt=2; Ksrc=64; ldm=64; coloff=0; p-=2048; }
            else if (p < 6144)  { layer=2; base=WB3;  nkt=2; Ksrc=64; ldm=64; coloff=0; p-=4096; }
            else if (p < 8192)  { layer=3; base=WB4;  nkt=2; Ksrc=64; ldm=65; coloff=1; p-=6144; }
            else if (p < 11264) { layer=4; base=WBR1; nkt=3; Ksrc=80; ldm=64; coloff=0; p-=8192; }
            else                { layer=5; base=WBR2; nkt=2; Ksrc=64; ldm=64; coloff=0; p-=11264; }
            const float* W = Wp[layer];
            int j = p & 3, ln = (p >> 2) & 63, fk = p >> 8;
            int qq = ln >> 4, rr = ln & 15;
            int kt = fk % nkt, it = fk / nkt;
            int m  = it * 16 + rr;
            int k0 = kt * 32 + qq * 8 + 2 * j;
            float w0 = (k0     < Ksrc) ? W[(size_t)k0 * ldm + m + coloff] * 256.0f : 0.0f;
            float w1 = (k0 + 1 < Ksrc) ? W[(size_t)(k0 + 1) * ldm + m + coloff] * 256.0f : 0.0f;
            u16 h0, l0, h1, l1; hsplit(w0, h0, l0); hsplit(w1, h1, l1);
            int half = nkt * 1024;
            int idx  = base + (fk * 64 + ln) * 4 + j;
            lds[idx]        = (u32)h0 | ((u32)h1 << 16);
            lds[idx + half] = (u32)l0 | ((u32)l1 << 16);
        }
        if (tid < 24) {
            float sc, wl; window_scale(tid, iter, sc, wl);
            lds[SWOFF + 2*tid]     = __float_as_uint(sc);
            lds[SWOFF + 2*tid + 1] = __float_as_uint(wl);
        }
        if (tid >= 64 && tid < 128)  lds[W4C + tid - 64]  = __float_as_uint(W4[(size_t)(tid - 64) * 65]);
        if (tid >= 128 && tid < 320) lds[R3C + tid - 128] = __float_as_uint(R3[tid - 128]);
        if (tid >= 320 && tid < 392) lds[SHF + tid - 320] = (u32)shifts[tid - 320];
    }
    __syncthreads();   // blob/tables ready; read-only hereafter

    const int pbase = SPLIT ? blockIdx.x * ppb : 0;

    if constexpr (SPLIT) {
        // ---- phase 1: LEVEL-MAJOR encode of this block's points into pf ----
        for (int cp = 0; cp < ppb; cp += 1024 * 4) {
            float lx[4], ly[4], lz[4];
            bool  lv[4];
            #pragma unroll
            for (int j = 0; j < 4; j++) {
                int off = cp + j * 1024 + tid;
                int p = pbase + off;
                lv[j] = (off < ppb) && (p < n);
                lx[j] = 0.f; ly[j] = 0.f; lz[j] = 0.f;
                if (lv[j]) { lx[j] = pos[3*p]; ly[j] = pos[3*p+1]; lz[j] = pos[3*p+2]; }
            }
            for (int l = 0; l < LVLS; l++) {
                float sc = __uint_as_float(lds[SWOFF + 2*l]);
                float wl = __uint_as_float(lds[SWOFF + 2*l + 1]);
                int sx = (int)lds[SHF + 3*l], sy = (int)lds[SHF + 3*l + 1], sz = (int)lds[SHF + 3*l + 2];
                const float* tl = tables + 2 * ((size_t)l * CAPN);
                #pragma unroll 2
                for (int j = 0; j < 4; j++) {
                    if (!lv[j]) continue;
                    float f0, f1;
                    hash_level(lx[j], ly[j], lz[j], sc, wl, sx, sy, sz, tl, f0, f1);
                    int p = pbase + cp + j * 1024 + tid;
                    pf[(size_t)l * n + p] = (u32)f2h(f0 * 256.0f) | ((u32)f2h(f1 * 256.0f) << 16);
                }
                __syncthreads();   // keep the block's 16 waves level-aligned
            }
        }
        __syncthreads();           // pf complete for this block's range
    }

    // ---- phase 2: register-resident MLP chain (no barriers, no act LDS) ----
    const int iters = SPLIT ? (ppb / (WAVES * TPW)) : nbat;
    for (int bb0 = 0; bb0 < iters; bb0++) {
        int tstart;
        if constexpr (SPLIT) {
            tstart = pbase + (bb0 * WAVES + wave) * TPW;
        } else {
            int bb = blockIdx.x + bb0 * gridDim.x;
            if (bb >= nbat) break;
            tstart = (bb * WAVES + wave) * TPW;
        }
        if (tstart >= n) continue;
        const int i    = tstart + r;
        const bool valid = (i < n);

        float px = 0.f, py = 0.f, pz = 0.f;
        if (valid) { px = pos[3*i]; py = pos[3*i+1]; pz = pos[3*i+2]; }

        // E[it][j] = packhl feature it*16+q*4+j of point r
        u32 E[6][4];
        #pragma unroll
        for (int j = 0; j < 4; j++) { E[4][j] = 0u; E[5][j] = 0u; }

        if constexpr (SPLIT) {
            // hash features from pf: lane (q,r) holds levels it*8+2q, +1 (it<3)
            #pragma unroll
            for (int it = 0; it < 3; it++) {
                int l0 = it * 8 + q * 2;
                u32 v0 = valid ? pf[(size_t)l0 * n + i] : 0u;
                u32 v1 = valid ? pf[(size_t)(l0 + 1) * n + i] : 0u;
                E[it][0] = v0 << 16;
                E[it][1] = v0 & 0xffff0000u;
                E[it][2] = v1 << 16;
                E[it][3] = v1 & 0xffff0000u;
            }
        } else {
            // fallback: per-lane serial encode of its 6 levels
            #pragma unroll
            for (int it = 0; it < 3; it++) {
                #pragma unroll
                for (int dl = 0; dl < 2; dl++) {
                    int l = it * 8 + q * 2 + dl;
                    float sc = __uint_as_float(lds[SWOFF + 2*l]);
                    float wl = __uint_as_float(lds[SWOFF + 2*l + 1]);
                    float f0, f1;
                    hash_level(px, py, pz, sc, wl,
                               (int)lds[SHF + 3*l], (int)lds[SHF + 3*l + 1], (int)lds[SHF + 3*l + 2],
                               tables + 2 * ((size_t)l * CAPN), f0, f1);
                    E[it][2*dl]     = (u32)f2h(f0 * 256.0f) << 16;
                    E[it][2*dl + 1] = (u32)f2h(f1 * 256.0f) << 16;
                }
            }
        }
        // pos features 48..50 (it=3, q=0); rest of it=3 zeros
        if (q == 0) {
            E[3][0] = packhl(px * 256.0f);
            E[3][1] = packhl(py * 256.0f);
            E[3][2] = packhl(pz * 256.0f);
            E[3][3] = 0u;
        } else {
            #pragma unroll
            for (int j = 0; j < 4; j++) E[3][j] = 0u;
        }

        f32x4 acc[4];
        mfma_layer_reg<2>(lds + WB1, E, lane, acc); epilogue_reg(acc, b1, lane, E);
        mfma_layer_reg<2>(lds + WB2, E, lane, acc); epilogue_reg(acc, b2, lane, E);
        mfma_layer_reg<2>(lds + WB3, E, lane, acc); epilogue_reg(acc, b3, lane, E);

        // density: partial dot over held features, reduce over 4-lane group
        {
            float t = 0.f;
            #pragma unroll
            for (int it = 0; it < 4; it++)
                #pragma unroll
                for (int j = 0; j < 4; j++)
                    t = fmaf(unpackhl(E[it][j]),
                             __uint_as_float(lds[W4C + it * 16 + q * 4 + j]), t);
            t += __shfl_xor(t, 16);
            t += __shfl_xor(t, 32);
            float s = fmaf(t, 0x1p-8f, b4[0]);
            if (q == 0 && valid) out[(size_t)3 * n + i] = fmaxf(s, 0.f) + log1pf(expf(-fabsf(s)));
        }

        mfma_layer_reg<2>(lds + WB4, E, lane, acc);   // W4 cols 1..64
        epilogue_reg(acc, b4 + 1, lane, E);

        // SH -> features 64..79: lane (q,r) computes sh[q*4+j] -> E[4][j]
        {
            float dx = 0.f, dy = 0.f, dz = 0.f;
            if (valid) { dx = dirs[3*i]; dy = dirs[3*i+1]; dz = dirs[3*i+2]; }
            float xx = dx*dx, yy = dy*dy, zz = dz*dz;
            float sh[16];
            sh[0]  = 0.28209479177387814f;
            sh[1]  = -0.48860251190291987f * dy;
            sh[2]  = 0.48860251190291987f * dz;
            sh[3]  = -0.48860251190291987f * dx;
            sh[4]  = 1.0925484305920792f * dx * dy;
            sh[5]  = -1.0925484305920792f * dy * dz;
            sh[6]  = 0.94617469575756f * zz - 0.31539156525252f;
            sh[7]  = -1.0925484305920792f * dx * dz;
            sh[8]  = 0.5462742152960396f * (xx - yy);
            sh[9]  = -0.5900435899266435f * dy * (3.0f * xx - yy);
            sh[10] = 2.890611442640554f * dx * dy * dz;
            sh[11] = -0.4570457994644657f * dy * (4.0f * zz - xx - yy);
            sh[12] = 0.37317633259011546f * dz * (2.0f * zz - 3.0f * xx - 3.0f * yy);
            sh[13] = -0.4570457994644657f * dx * (4.0f * zz - xx - yy);
            sh[14] = 1.445305721320277f * dz * (xx - yy);
            sh[15] = -0.5900435899266435f * dx * (xx - 3.0f * yy);
            #pragma unroll
            for (int j = 0; j < 4; j++) E[4][j] = packhl(sh[q * 4 + j] * 256.0f);
        }

        mfma_layer_reg<3>(lds + WBR1, E, lane, acc);  // kt=2 uses E[4] (SH), E[5]=0
        epilogue_reg(acc, rb1, lane, E);
        mfma_layer_reg<2>(lds + WBR2, E, lane, acc);
        epilogue_reg(acc, rb2, lane, E);

        // R3 + sigmoid: partial dot over held features, reduce over 4-lane group
        {
            float t0 = 0.f, t1 = 0.f, t2 = 0.f;
            #pragma unroll
            for (int it = 0; it < 4; it++)
                #pragma unroll
                for (int j = 0; j < 4; j++) {
                    int f = it * 16 + q * 4 + j;
                    float xv = unpackhl(E[it][j]);
                    t0 = fmaf(xv, __uint_as_float(lds[R3C + 3*f + 0]), t0);
                    t1 = fmaf(xv, __uint_as_float(lds[R3C + 3*f + 1]), t1);
                    t2 = fmaf(xv, __uint_as_float(lds[R3C + 3*f + 2]), t2);
                }
            t0 += __shfl_xor(t0, 16); t0 += __shfl_xor(t0, 32);
            t1 += __shfl_xor(t1, 16); t1 += __shfl_xor(t1, 32);
            t2 += __shfl_xor(t2, 16); t2 += __shfl_xor(t2, 32);
            if (q == 0 && valid) {
                float y0 = fmaf(t0, 0x1p-8f, rb3[0]);
                float y1 = fmaf(t1, 0x1p-8f, rb3[1]);
                float y2 = fmaf(t2, 0x1p-8f, rb3[2]);
                out[(size_t)3 * i + 0] = sigmoid_f(y0);
                out[(size_t)3 * i + 1] = sigmoid_f(y1);
                out[(size_t)3 * i + 2] = sigmoid_f(y2);
            }
        }
    }
}

extern "C" void kernel_launch(void* const* d_in, const int* in_sizes, int n_in,
                              void* d_out, int out_size, void* d_ws, size_t ws_size,
                              hipStream_t stream) {
    int n = in_sizes[0] / 3;
    int ntiles = (n + TPW - 1) / TPW;
    int nbat = (ntiles + WAVES - 1) / WAVES;
    size_t ldsb = (size_t)LDS_U32 * 4;   // 108032 B

    size_t need = (size_t)LVLS * (size_t)n * 4;
    bool split = (ws_size >= need) && (n >= 256 * WAVES * TPW);

    if (split) {
        int cpb = (n + 255) / 256;                              // points per block (raw)
        int wtp = WAVES * TPW;                                  // 256
        int ppb = (cpb + wtp - 1) / wtp * wtp;                  // round up to 256
        hipFuncSetAttribute(reinterpret_cast<const void*>(nerf_persist<true>),
                            hipFuncAttributeMaxDynamicSharedMemorySize, (int)ldsb);
        nerf_persist<true><<<256, 1024, ldsb, stream>>>(
            (const float*)d_in[0], (const float*)d_in[1], (const int*)d_in[2],
            (const float*)d_in[3], (const int*)d_in[4],
            (const float*)d_in[5],  (const float*)d_in[6],
            (const float*)d_in[7],  (const float*)d_in[8],
            (const float*)d_in[9],  (const float*)d_in[10],
            (const float*)d_in[11], (const float*)d_in[12],
            (const float*)d_in[13], (const float*)d_in[14],
            (const float*)d_in[15], (const float*)d_in[16],
            (const float*)d_in[17], (const float*)d_in[18],
            (u32*)d_ws, (float*)d_out, n, nbat, ppb);
    } else {
        int grid = nbat < 256 ? nbat : 256;
        hipFuncSetAttribute(reinterpret_cast<const void*>(nerf_persist<false>),
                            hipFuncAttributeMaxDynamicSharedMemorySize, (int)ldsb);
        nerf_persist<false><<<grid, 1024, ldsb, stream>>>(
            (const float*)d_in[0], (const float*)d_in[1], (const int*)d_in[2],
            (const float*)d_in[3], (const int*)d_in[4],
            (const float*)d_in[5],  (const float*)d_in[6],
            (const float*)d_in[7],  (const float*)d_in[8],
            (const float*)d_in[9],  (const float*)d_in[10],
            (const float*)d_in[11], (const float*)d_in[12],
            (const float*)d_in[13], (const float*)d_in[14],
            (const float*)d_in[15], (const float*)d_in[16],
            (const float*)d_in[17], (const float*)d_in[18],
            (u32*)d_ws, (float*)d_out, n, nbat, 0);
    }
}